// Round 7
// baseline (375.335 us; speedup 1.0000x reference)
//
#include <hip/hip_runtime.h>

#define N_NODES 50000
#define N_EDGES 600000
#define N_GRAPHS 2048
#define EMB 128
#define TDIM 384
#define TS_LD 392               // padded LDS row stride (shorts): 2-way bank alias only
#define HN (N_NODES * EMB)
#define SCAN_NB ((N_NODES + 255) / 256)   // 196
#define DEG_STRIDE 32           // one degree counter per 128B cache line

// merged-prepass block ranges (384 threads/block)
#define PRE_ATOM_NB 8334        // 6 nodes/block, FULL wave per node (async LDS gathers)
#define PRE_HIST_NB 1563        // ceil(600000/384)
#define PRE_WCONV_NB 384        // one (layer,col) per block
#define PRE_GB_NB 131           // ceil(50000/384)

typedef __attribute__((ext_vector_type(8))) short bf16x8;
typedef __attribute__((ext_vector_type(4))) float f32x4;
#define MFMA_BF16(a, b, c) __builtin_amdgcn_mfma_f32_16x16x32_bf16(a, b, c, 0, 0, 0)

#define AS1 __attribute__((address_space(1)))
#define AS3 __attribute__((address_space(3)))
__device__ inline void gl_lds16(const void* g, void* l) {
  // async global->LDS, 16B/lane: LDS dest = l + lane*16 (wave-uniform base), no dest VGPRs
  __builtin_amdgcn_global_load_lds((const AS1 void*)g, (AS3 void*)l, 16, 0, 0);
}

__device__ inline unsigned short f2bf(float f) {
  unsigned int u = __float_as_uint(f);
  u += 0x7fffu + ((u >> 16) & 1u);   // round to nearest even
  return (unsigned short)(u >> 16);
}
__device__ inline float bf2f(unsigned short b) {
  return __uint_as_float(((unsigned int)b) << 16);
}
__device__ inline bf16x8 pack8(float4 lo, float4 hi) {
  bf16x8 r;
  r[0] = (short)f2bf(lo.x); r[1] = (short)f2bf(lo.y);
  r[2] = (short)f2bf(lo.z); r[3] = (short)f2bf(lo.w);
  r[4] = (short)f2bf(hi.x); r[5] = (short)f2bf(hi.y);
  r[6] = (short)f2bf(hi.z); r[7] = (short)f2bf(hi.w);
  return r;
}

// ---------------- merged prepass: atom-encoder | degree-hist+rank | W-transpose | graph-bounds -----
// Hist: returning atomic, one counter per 128B line; rank[e] = old value -> scatter is
// atomic-free (round-4/5: net -12.5us vs atomic scatter, despite returning-atomic cost).
__global__ __launch_bounds__(384) void k_pre(const int* __restrict__ x,
                                             const float* __restrict__ atom_emb,
                                             unsigned short* __restrict__ h_bf,
                                             const int* __restrict__ ei,
                                             int* __restrict__ degP,   // [N_NODES*DEG_STRIDE]
                                             int* __restrict__ rank,   // [N_EDGES]
                                             const float* __restrict__ W,
                                             unsigned short* __restrict__ wt,
                                             const int* __restrict__ batch,
                                             int* __restrict__ gs) {
  __shared__ float sb[6 * 1280];   // 30 KB: 6 waves x (9 rows of 128f + scratch tail)
  int blk = blockIdx.x;
  if (blk < PRE_ATOM_NB) {
    const int wv = threadIdx.x >> 6;
    const int lane = threadIdx.x & 63;
    int n = blk * 6 + wv;
    if (n < N_NODES) {
      const int nu = __builtin_amdgcn_readfirstlane(n);
      const int* xr = x + nu * 9;
      int ix[9];
#pragma unroll
      for (int c = 0; c < 9; ++c) ix[c] = xr[c];   // wave-uniform -> s_loads
      float* wbase = sb + wv * 1280;
      const int half = lane >> 5;       // 0: lanes 0-31, 1: lanes 32-63
      const int sub16 = lane & 31;      // 16B slot within the row
#pragma unroll
      for (int j = 0; j < 4; ++j) {
        int c = 2 * j + half;
        const float* g = atom_emb + (size_t)(c * 100 + ix[c]) * EMB + sub16 * 4;
        gl_lds16(g, wbase + j * 256);   // row 2j -> +j*1024B, row 2j+1 -> +j*1024B+512B
      }
      {  // row 8: both halves load the same 512B (lanes 32-63 land in scratch tail)
        const float* g = atom_emb + (size_t)(8 * 100 + ix[8]) * EMB + sub16 * 4;
        gl_lds16(g, wbase + 1024);
      }
      asm volatile("s_waitcnt vmcnt(0)" ::: "memory");
      float2 acc = {0.f, 0.f};
#pragma unroll
      for (int c = 0; c < 9; ++c) {     // row c at wbase + c*128 floats
        float2 v = *(const float2*)(wbase + c * 128 + lane * 2);
        acc.x += v.x; acc.y += v.y;
      }
      *(ushort2*)(h_bf + (size_t)nu * EMB + lane * 2) = ushort2{f2bf(acc.x), f2bf(acc.y)};
    }
    return;
  }
  blk -= PRE_ATOM_NB;
  if (blk < PRE_HIST_NB) {
    int e = blk * 384 + threadIdx.x;
    if (e < N_EDGES) {
      int d = ei[N_EDGES + e];
      rank[e] = atomicAdd(&degP[(size_t)d * DEG_STRIDE], 1);  // private line per node
    }
    return;
  }
  blk -= PRE_HIST_NB;
  if (blk < PRE_WCONV_NB) {
    int layer = blk >> 7, c = blk & 127, k = threadIdx.x;
    float v = W[(((layer * 3 + (k >> 7)) * 128) + (k & 127)) * 128 + c];
    wt[(size_t)blk * 384 + k] = f2bf(v);
    return;
  }
  blk -= PRE_WCONV_NB;
  {
    int i = blk * 384 + threadIdx.x;
    if (i < N_NODES) {
      int b = batch[i];
      int bp = (i == 0) ? -1 : batch[i - 1];
      for (int g = bp + 1; g <= b; ++g) gs[g] = i;
      if (i == N_NODES - 1) {
        for (int g = b + 1; g <= N_GRAPHS; ++g) gs[g] = N_NODES;
      }
    }
  }
}

// ---------------- CSR scan ----------------
__global__ __launch_bounds__(256) void k_scan_a(const int* __restrict__ degP,
                                                int* __restrict__ row_start,
                                                int* __restrict__ partials) {
  __shared__ int s[256];
  const int tid = threadIdx.x;
  const int i = blockIdx.x * 256 + tid;
  int v = (i < N_NODES) ? degP[(size_t)i * DEG_STRIDE] : 0;
  s[tid] = v;
  __syncthreads();
  for (int off = 1; off < 256; off <<= 1) {
    int t = (tid >= off) ? s[tid - off] : 0;
    __syncthreads();
    s[tid] += t;
    __syncthreads();
  }
  if (i < N_NODES) row_start[i] = s[tid] - v;
  if (tid == 255) partials[blockIdx.x] = s[255];
}

__global__ __launch_bounds__(256) void k_scan_b(int* __restrict__ partials,
                                                int* __restrict__ row_start) {
  __shared__ int s[256];
  const int tid = threadIdx.x;
  int v = (tid < SCAN_NB) ? partials[tid] : 0;
  s[tid] = v;
  __syncthreads();
  for (int off = 1; off < 256; off <<= 1) {
    int t = (tid >= off) ? s[tid - off] : 0;
    __syncthreads();
    s[tid] += t;
    __syncthreads();
  }
  if (tid < SCAN_NB) partials[tid] = s[tid] - v;
  if (tid == 255) row_start[N_NODES] = s[255];
}

__global__ __launch_bounds__(256) void k_scan_c(int* __restrict__ row_start,
                                                const int* __restrict__ partials) {
  const int i = blockIdx.x * 256 + threadIdx.x;
  if (i < N_NODES) row_start[i] += partials[blockIdx.x];
}

// Scatter edges into CSR order -- ATOMIC-FREE: pos = row_start[dst] + rank[e].
__global__ __launch_bounds__(256) void k_scatter(const int* __restrict__ ei,
                                                 const int* __restrict__ ea,
                                                 const int* __restrict__ rank,
                                                 const int* __restrict__ row_start,
                                                 int2* __restrict__ sorted_se) {
  int e = blockIdx.x * 256 + threadIdx.x;
  if (e >= N_EDGES) return;
  int src = ei[e], dst = ei[N_EDGES + e];
  int pos = row_start[dst] + rank[e];
  int eap = ea[e * 3 + 0] | (ea[e * 3 + 1] << 3) | (ea[e * 3 + 2] << 6);
  sorted_se[pos] = int2{src, eap};
}

// ---------------- Edge aggregation: QUARTER-WAVE per node, UNROLL-16 ----------------
// k_agg is memory-LATENCY-bound (round-1 counters; round-6 falsified the divergence
// theory -- bucketing bought 0). The lever is outstanding bytes: 16-edge chunks put
// 4 nodes x 16 edges x 16B = 16 KB in flight per wave (2x round-5's 8 KB).
// Full 16-chunks run an UNCHECKED fast path; only the final partial chunk pays
// bounds logic (clamped loads re-hit the same line -> cheap).
__global__ __launch_bounds__(256) void k_agg(const int2* __restrict__ sorted_se,
                                             const int* __restrict__ row_start,
                                             const float* __restrict__ bl,  // bond_emb[layer]: [3][8][3]
                                             const unsigned short* __restrict__ h_bf,
                                             unsigned short* __restrict__ t_bf) {
  __shared__ float4 combo[512];  // 8 KB
  for (int c = threadIdx.x; c < 512; c += 256) {
    int a0 = c & 7, a1 = (c >> 3) & 7, a2 = (c >> 6) & 7;
    combo[c] = float4{bl[a0 * 3 + 0] + bl[24 + a1 * 3 + 0] + bl[48 + a2 * 3 + 0],
                      bl[a0 * 3 + 1] + bl[24 + a1 * 3 + 1] + bl[48 + a2 * 3 + 1],
                      bl[a0 * 3 + 2] + bl[24 + a1 * 3 + 2] + bl[48 + a2 * 3 + 2], 0.f};
  }
  __syncthreads();
  const int node = blockIdx.x * 16 + (threadIdx.x >> 4);  // quarter-wave per node
  const int sub = threadIdx.x & 15;                       // cols sub*8..+7
  const int beg = row_start[node], end = row_start[node + 1];
  float4 l0 = {0.f, 0.f, 0.f, 0.f}, h0 = l0;   // channel 0: cols lo/hi
  float4 l1 = l0, h1 = l0;                     // channel 1
  float4 l2 = l0, h2 = l0;                     // channel 2
  int e = beg;
  const int full_end = beg + ((end - beg) & ~15);
  for (; e < full_end; e += 16) {          // fast path: no bounds logic
    int2 se[16];
#pragma unroll
    for (int j = 0; j < 16; ++j) se[j] = sorted_se[e + j];
    bf16x8 u[16];
#pragma unroll
    for (int j = 0; j < 16; ++j)
      u[j] = *(const bf16x8*)(h_bf + (size_t)se[j].x * EMB + sub * 8);
#pragma unroll
    for (int j = 0; j < 16; ++j) {
      float4 w = combo[se[j].y];
      float4 vlo = {bf2f((unsigned short)u[j][0]), bf2f((unsigned short)u[j][1]),
                    bf2f((unsigned short)u[j][2]), bf2f((unsigned short)u[j][3])};
      float4 vhi = {bf2f((unsigned short)u[j][4]), bf2f((unsigned short)u[j][5]),
                    bf2f((unsigned short)u[j][6]), bf2f((unsigned short)u[j][7])};
      l0 += vlo * w.x; h0 += vhi * w.x;
      l1 += vlo * w.y; h1 += vhi * w.y;
      l2 += vlo * w.z; h2 += vhi * w.z;
    }
  }
  if (e < end) {                           // tail chunk: clamped + weight-selected
    int2 se[16];
#pragma unroll
    for (int j = 0; j < 16; ++j) {
      int idx = e + j;
      se[j] = sorted_se[idx < end ? idx : end - 1];
    }
    bf16x8 u[16];
#pragma unroll
    for (int j = 0; j < 16; ++j)
      u[j] = *(const bf16x8*)(h_bf + (size_t)se[j].x * EMB + sub * 8);
#pragma unroll
    for (int j = 0; j < 16; ++j) {
      float4 w = (e + j < end) ? combo[se[j].y] : float4{0.f, 0.f, 0.f, 0.f};
      float4 vlo = {bf2f((unsigned short)u[j][0]), bf2f((unsigned short)u[j][1]),
                    bf2f((unsigned short)u[j][2]), bf2f((unsigned short)u[j][3])};
      float4 vhi = {bf2f((unsigned short)u[j][4]), bf2f((unsigned short)u[j][5]),
                    bf2f((unsigned short)u[j][6]), bf2f((unsigned short)u[j][7])};
      l0 += vlo * w.x; h0 += vhi * w.x;
      l1 += vlo * w.y; h1 += vhi * w.y;
      l2 += vlo * w.z; h2 += vhi * w.z;
    }
  }
  size_t base = (size_t)node * TDIM + sub * 8;
  *(bf16x8*)(t_bf + base)       = pack8(l0, h0);
  *(bf16x8*)(t_bf + base + 128) = pack8(l1, h1);
  *(bf16x8*)(t_bf + base + 256) = pack8(l2, h2);
}

// ---------------- MFMA GEMM: stage 32 t-rows into LDS, per-wave GEMM, bf16 residual ----------------
// Block 512 thr = 8 waves; 32 nodes/block; grid 1563. Wave wv owns cols wv*16..+15:
// 12 resident B-frags, 2 row-tiles (A via ds_read_b128), 12 chained MFMAs each.
// A-frag: A[m=lane&15][k=(lane>>4)*8+j]; B-frag: B[k][n=lane&15];
// C/D: col=lane&15, row=(lane>>4)*4+reg.
__global__ __launch_bounds__(512) void k_gemm(const unsigned short* __restrict__ t_bf,
                                              const unsigned short* __restrict__ wt,  // [128][384]
                                              const float* __restrict__ bl,  // [3][128]
                                              const unsigned short* __restrict__ h_in_bf,
                                              unsigned short* __restrict__ h_out_bf,
                                              int do_relu) {
  __shared__ unsigned short ts[32 * TS_LD];   // 24.5 KB
  const int nb = blockIdx.x * 32;
  for (int i = threadIdx.x; i < 32 * 48; i += 512) {
    int r = i / 48, cc = i % 48;
    bf16x8 v = {};
    int row = nb + r;
    if (row < N_NODES) v = *(const bf16x8*)(t_bf + (size_t)row * TDIM + cc * 8);
    *(bf16x8*)(ts + r * TS_LD + cc * 8) = v;
  }
  __syncthreads();

  const int wv = threadIdx.x >> 6;
  const int lane = threadIdx.x & 63;
  const int m = lane & 15;
  const int kq = lane >> 4;
  const int c = wv * 16 + m;

  const unsigned short* pB = wt + (size_t)c * TDIM + kq * 8;
  bf16x8 B[12];
#pragma unroll
  for (int kc = 0; kc < 12; ++kc) B[kc] = *(const bf16x8*)(pB + kc * 32);

  const float bias = bl[c] + bl[128 + c] + bl[256 + c];

#pragma unroll
  for (int rt = 0; rt < 2; ++rt) {
    const unsigned short* pA = ts + (rt * 16 + m) * TS_LD + kq * 8;
    bf16x8 A[12];
#pragma unroll
    for (int kc = 0; kc < 12; ++kc) A[kc] = *(const bf16x8*)(pA + kc * 32);
    f32x4 acc = {0.f, 0.f, 0.f, 0.f};
#pragma unroll
    for (int kc = 0; kc < 12; ++kc) acc = MFMA_BF16(A[kc], B[kc], acc);
#pragma unroll
    for (int r = 0; r < 4; ++r) {
      int row = nb + rt * 16 + kq * 4 + r;
      if (row < N_NODES) {
        size_t idx = (size_t)row * EMB + c;
        float v = acc[r] + bias;
        if (do_relu) v = fmaxf(v, 0.f);
        float hn = bf2f(h_in_bf[idx]) + v;
        h_out_bf[idx] = f2bf(hn);
      }
    }
  }
}

// ---------------- fused mean-pool + head: block g reduces its contiguous node range ----------------
__global__ __launch_bounds__(128) void k_head(const unsigned short* __restrict__ h_bf,
                                              const int* __restrict__ gs,
                                              const float* __restrict__ fc1_w,
                                              const float* __restrict__ fc1_b,
                                              const float* __restrict__ fc2_w,
                                              const float* __restrict__ fc2_b,
                                              float* __restrict__ out) {
  __shared__ float hg[EMB];
  __shared__ float red[EMB];
  int g = blockIdx.x, e = threadIdx.x;
  int ns = gs[g], ne = gs[g + 1];
  float acc = 0.f;
  for (int n = ns; n < ne; ++n) acc += bf2f(h_bf[(size_t)n * EMB + e]);
  float cnt = fmaxf((float)(ne - ns), 1.f);
  hg[e] = acc / cnt;
  __syncthreads();
  float a2 = fc1_b[e];
  for (int j = 0; j < EMB; ++j) a2 += hg[j] * fc1_w[j * EMB + e];
  red[e] = a2 * fc2_w[e];
  __syncthreads();
  for (int s = 64; s > 0; s >>= 1) {
    if (e < s) red[e] += red[e + s];
    __syncthreads();
  }
  if (e == 0) out[g] = red[0] + fc2_b[0];
}

extern "C" void kernel_launch(void* const* d_in, const int* in_sizes, int n_in,
                              void* d_out, int out_size, void* d_ws, size_t ws_size,
                              hipStream_t stream) {
  const int*   x        = (const int*)d_in[0];
  const int*   ei       = (const int*)d_in[1];
  const int*   ea       = (const int*)d_in[2];
  const int*   batch    = (const int*)d_in[3];
  const float* atom_emb = (const float*)d_in[4];
  const float* bond_emb = (const float*)d_in[5];
  const float* W        = (const float*)d_in[6];
  const float* b        = (const float*)d_in[7];
  const float* fc1_w    = (const float*)d_in[8];
  const float* fc1_b    = (const float*)d_in[9];
  const float* fc2_w    = (const float*)d_in[10];
  const float* fc2_b    = (const float*)d_in[11];
  float* out = (float*)d_out;

  char* p = (char*)d_ws;
  auto alloc = [&](size_t bytes) { char* r = p; p += (bytes + 255) & ~(size_t)255; return r; };
  unsigned short* h0_bf      = (unsigned short*)alloc((size_t)HN * 2);
  unsigned short* h1_bf      = (unsigned short*)alloc((size_t)HN * 2);
  unsigned short* t_bf       = (unsigned short*)alloc((size_t)N_NODES * TDIM * 2);
  unsigned short* wt         = (unsigned short*)alloc((size_t)3 * 128 * TDIM * 2);
  int*            gs         = (int*)alloc((size_t)(N_GRAPHS + 1) * 4);
  int*            degP       = (int*)alloc((size_t)N_NODES * DEG_STRIDE * 4);  // 6.4 MB
  int*            rank       = (int*)alloc((size_t)N_EDGES * 4);
  int*            row_start  = (int*)alloc((size_t)(N_NODES + 1) * 4);
  int*            partials   = (int*)alloc(256 * 4);
  int2*           sorted_se  = (int2*)alloc((size_t)(N_EDGES + 16) * 8);

  hipMemsetAsync(degP, 0, (size_t)N_NODES * DEG_STRIDE * sizeof(int), stream);
  const int pre_blocks = PRE_ATOM_NB + PRE_HIST_NB + PRE_WCONV_NB + PRE_GB_NB;
  k_pre<<<pre_blocks, 384, 0, stream>>>(x, atom_emb, h0_bf, ei, degP, rank, W, wt, batch, gs);
  k_scan_a<<<SCAN_NB, 256, 0, stream>>>(degP, row_start, partials);
  k_scan_b<<<1, 256, 0, stream>>>(partials, row_start);
  k_scan_c<<<SCAN_NB, 256, 0, stream>>>(row_start, partials);
  k_scatter<<<(N_EDGES + 255) / 256, 256, 0, stream>>>(ei, ea, rank, row_start, sorted_se);

  unsigned short* hib = h0_bf;
  unsigned short* hob = h1_bf;
  const int gemm_blocks = (N_NODES + 31) / 32;  // 1563
  for (int layer = 0; layer < 3; ++layer) {
    k_agg<<<N_NODES / 16, 256, 0, stream>>>(sorted_se, row_start, bond_emb + layer * 72,
                                            hib, t_bf);
    k_gemm<<<gemm_blocks, 512, 0, stream>>>(
        t_bf, wt + (size_t)layer * 128 * TDIM, b + layer * 3 * EMB,
        hib, hob, layer < 2 ? 1 : 0);
    unsigned short* tb = hib; hib = hob; hob = tb;
  }
  // final h is in hib (h1_bf after 3 swaps)

  k_head<<<N_GRAPHS, 128, 0, stream>>>(hib, gs, fc1_w, fc1_b, fc2_w, fc2_b, out);
}

// Round 8
// 343.706 us; speedup vs baseline: 1.0920x; 1.0920x over previous
//
#include <hip/hip_runtime.h>

#define N_NODES 50000
#define N_EDGES 600000
#define N_GRAPHS 2048
#define EMB 128
#define TDIM 384
#define TS_LD 392               // padded LDS row stride (shorts): 2-way bank alias only
#define HN (N_NODES * EMB)
#define SCAN_NB ((N_NODES + 255) / 256)   // 196
#define DEG_STRIDE 32           // one degree counter per 128B cache line
#define GROWS 64                // k_gemm rows per block

// merged-prepass block ranges (384 threads/block)
#define PRE_ATOM_NB 8334        // 6 nodes/block, FULL wave per node (async LDS gathers)
#define PRE_HIST_NB 1563        // ceil(600000/384)
#define PRE_WCONV_NB 384        // one (layer,col) per block
#define PRE_GB_NB 131           // ceil(50000/384)

typedef __attribute__((ext_vector_type(8))) short bf16x8;
typedef __attribute__((ext_vector_type(4))) float f32x4;
#define MFMA_BF16(a, b, c) __builtin_amdgcn_mfma_f32_16x16x32_bf16(a, b, c, 0, 0, 0)

#define AS1 __attribute__((address_space(1)))
#define AS3 __attribute__((address_space(3)))
__device__ inline void gl_lds16(const void* g, void* l) {
  // async global->LDS, 16B/lane: LDS dest = l + lane*16 (wave-uniform base), no dest VGPRs
  __builtin_amdgcn_global_load_lds((const AS1 void*)g, (AS3 void*)l, 16, 0, 0);
}

__device__ inline unsigned short f2bf(float f) {
  unsigned int u = __float_as_uint(f);
  u += 0x7fffu + ((u >> 16) & 1u);   // round to nearest even
  return (unsigned short)(u >> 16);
}
__device__ inline float bf2f(unsigned short b) {
  return __uint_as_float(((unsigned int)b) << 16);
}
__device__ inline bf16x8 pack8(float4 lo, float4 hi) {
  bf16x8 r;
  r[0] = (short)f2bf(lo.x); r[1] = (short)f2bf(lo.y);
  r[2] = (short)f2bf(lo.z); r[3] = (short)f2bf(lo.w);
  r[4] = (short)f2bf(hi.x); r[5] = (short)f2bf(hi.y);
  r[6] = (short)f2bf(hi.z); r[7] = (short)f2bf(hi.w);
  return r;
}

// ---------------- merged prepass: atom-encoder | degree-hist+rank | W-transpose | graph-bounds -----
// Hist: returning atomic, one counter per 128B line; rank[e] = old value -> scatter is
// atomic-free (round-4/5: net -12.5us vs atomic scatter, despite returning-atomic cost).
__global__ __launch_bounds__(384) void k_pre(const int* __restrict__ x,
                                             const float* __restrict__ atom_emb,
                                             unsigned short* __restrict__ h_bf,
                                             const int* __restrict__ ei,
                                             int* __restrict__ degP,   // [N_NODES*DEG_STRIDE]
                                             int* __restrict__ rank,   // [N_EDGES]
                                             const float* __restrict__ W,
                                             unsigned short* __restrict__ wt,
                                             const int* __restrict__ batch,
                                             int* __restrict__ gs) {
  __shared__ float sb[6 * 1280];   // 30 KB: 6 waves x (9 rows of 128f + scratch tail)
  int blk = blockIdx.x;
  if (blk < PRE_ATOM_NB) {
    const int wv = threadIdx.x >> 6;
    const int lane = threadIdx.x & 63;
    int n = blk * 6 + wv;
    if (n < N_NODES) {
      const int nu = __builtin_amdgcn_readfirstlane(n);
      const int* xr = x + nu * 9;
      int ix[9];
#pragma unroll
      for (int c = 0; c < 9; ++c) ix[c] = xr[c];   // wave-uniform -> s_loads
      float* wbase = sb + wv * 1280;
      const int half = lane >> 5;       // 0: lanes 0-31, 1: lanes 32-63
      const int sub16 = lane & 31;      // 16B slot within the row
#pragma unroll
      for (int j = 0; j < 4; ++j) {
        int c = 2 * j + half;
        const float* g = atom_emb + (size_t)(c * 100 + ix[c]) * EMB + sub16 * 4;
        gl_lds16(g, wbase + j * 256);   // row 2j -> +j*1024B, row 2j+1 -> +j*1024B+512B
      }
      {  // row 8: both halves load the same 512B (lanes 32-63 land in scratch tail)
        const float* g = atom_emb + (size_t)(8 * 100 + ix[8]) * EMB + sub16 * 4;
        gl_lds16(g, wbase + 1024);
      }
      asm volatile("s_waitcnt vmcnt(0)" ::: "memory");
      float2 acc = {0.f, 0.f};
#pragma unroll
      for (int c = 0; c < 9; ++c) {     // row c at wbase + c*128 floats
        float2 v = *(const float2*)(wbase + c * 128 + lane * 2);
        acc.x += v.x; acc.y += v.y;
      }
      *(ushort2*)(h_bf + (size_t)nu * EMB + lane * 2) = ushort2{f2bf(acc.x), f2bf(acc.y)};
    }
    return;
  }
  blk -= PRE_ATOM_NB;
  if (blk < PRE_HIST_NB) {
    int e = blk * 384 + threadIdx.x;
    if (e < N_EDGES) {
      int d = ei[N_EDGES + e];
      rank[e] = atomicAdd(&degP[(size_t)d * DEG_STRIDE], 1);  // private line per node
    }
    return;
  }
  blk -= PRE_HIST_NB;
  if (blk < PRE_WCONV_NB) {
    int layer = blk >> 7, c = blk & 127, k = threadIdx.x;
    float v = W[(((layer * 3 + (k >> 7)) * 128) + (k & 127)) * 128 + c];
    wt[(size_t)blk * 384 + k] = f2bf(v);
    return;
  }
  blk -= PRE_WCONV_NB;
  {
    int i = blk * 384 + threadIdx.x;
    if (i < N_NODES) {
      int b = batch[i];
      int bp = (i == 0) ? -1 : batch[i - 1];
      for (int g = bp + 1; g <= b; ++g) gs[g] = i;
      if (i == N_NODES - 1) {
        for (int g = b + 1; g <= N_GRAPHS; ++g) gs[g] = N_NODES;
      }
    }
  }
}

// ---------------- CSR scan ----------------
__global__ __launch_bounds__(256) void k_scan_a(const int* __restrict__ degP,
                                                int* __restrict__ row_start,
                                                int* __restrict__ partials) {
  __shared__ int s[256];
  const int tid = threadIdx.x;
  const int i = blockIdx.x * 256 + tid;
  int v = (i < N_NODES) ? degP[(size_t)i * DEG_STRIDE] : 0;
  s[tid] = v;
  __syncthreads();
  for (int off = 1; off < 256; off <<= 1) {
    int t = (tid >= off) ? s[tid - off] : 0;
    __syncthreads();
    s[tid] += t;
    __syncthreads();
  }
  if (i < N_NODES) row_start[i] = s[tid] - v;
  if (tid == 255) partials[blockIdx.x] = s[255];
}

__global__ __launch_bounds__(256) void k_scan_b(int* __restrict__ partials,
                                                int* __restrict__ row_start) {
  __shared__ int s[256];
  const int tid = threadIdx.x;
  int v = (tid < SCAN_NB) ? partials[tid] : 0;
  s[tid] = v;
  __syncthreads();
  for (int off = 1; off < 256; off <<= 1) {
    int t = (tid >= off) ? s[tid - off] : 0;
    __syncthreads();
    s[tid] += t;
    __syncthreads();
  }
  if (tid < SCAN_NB) partials[tid] = s[tid] - v;
  if (tid == 255) row_start[N_NODES] = s[255];
}

__global__ __launch_bounds__(256) void k_scan_c(int* __restrict__ row_start,
                                                const int* __restrict__ partials) {
  const int i = blockIdx.x * 256 + threadIdx.x;
  if (i < N_NODES) row_start[i] += partials[blockIdx.x];
}

// Scatter edges into CSR order -- ATOMIC-FREE: pos = row_start[dst] + rank[e].
__global__ __launch_bounds__(256) void k_scatter(const int* __restrict__ ei,
                                                 const int* __restrict__ ea,
                                                 const int* __restrict__ rank,
                                                 const int* __restrict__ row_start,
                                                 int2* __restrict__ sorted_se) {
  int e = blockIdx.x * 256 + threadIdx.x;
  if (e >= N_EDGES) return;
  int src = ei[e], dst = ei[N_EDGES + e];
  int pos = row_start[dst] + rank[e];
  int eap = ea[e * 3 + 0] | (ea[e * 3 + 1] << 3) | (ea[e * 3 + 2] << 6);
  sorted_se[pos] = int2{src, eap};
}

// ---------------- Edge aggregation: QUARTER-WAVE per node, unroll-8 (round-5 local optimum) --------
// Ledger: bucketing (r6) -8us, unroll-16 (r7) -27us, half-wave (r0) -7us -- all reverted.
// 16 lanes x bf16x8 = full 256B row per gather; 4 nodes x 8 edges = 8 KB in flight/wave.
__global__ __launch_bounds__(256) void k_agg(const int2* __restrict__ sorted_se,
                                             const int* __restrict__ row_start,
                                             const float* __restrict__ bl,  // bond_emb[layer]: [3][8][3]
                                             const unsigned short* __restrict__ h_bf,
                                             unsigned short* __restrict__ t_bf) {
  __shared__ float4 combo[512];  // 8 KB
  for (int c = threadIdx.x; c < 512; c += 256) {
    int a0 = c & 7, a1 = (c >> 3) & 7, a2 = (c >> 6) & 7;
    combo[c] = float4{bl[a0 * 3 + 0] + bl[24 + a1 * 3 + 0] + bl[48 + a2 * 3 + 0],
                      bl[a0 * 3 + 1] + bl[24 + a1 * 3 + 1] + bl[48 + a2 * 3 + 1],
                      bl[a0 * 3 + 2] + bl[24 + a1 * 3 + 2] + bl[48 + a2 * 3 + 2], 0.f};
  }
  __syncthreads();
  const int node = blockIdx.x * 16 + (threadIdx.x >> 4);  // quarter-wave per node
  const int sub = threadIdx.x & 15;                       // cols sub*8..+7
  const int beg = row_start[node], end = row_start[node + 1];
  float4 l0 = {0.f, 0.f, 0.f, 0.f}, h0 = l0;   // channel 0: cols lo/hi
  float4 l1 = l0, h1 = l0;                     // channel 1
  float4 l2 = l0, h2 = l0;                     // channel 2
  int e = beg;
  const int full_end = beg + ((end - beg) & ~7);
  for (; e < full_end; e += 8) {           // fast path: no bounds logic
    int2 se[8];
#pragma unroll
    for (int j = 0; j < 8; ++j) se[j] = sorted_se[e + j];
    bf16x8 u[8];
#pragma unroll
    for (int j = 0; j < 8; ++j)
      u[j] = *(const bf16x8*)(h_bf + (size_t)se[j].x * EMB + sub * 8);
#pragma unroll
    for (int j = 0; j < 8; ++j) {
      float4 w = combo[se[j].y];
      float4 vlo = {bf2f((unsigned short)u[j][0]), bf2f((unsigned short)u[j][1]),
                    bf2f((unsigned short)u[j][2]), bf2f((unsigned short)u[j][3])};
      float4 vhi = {bf2f((unsigned short)u[j][4]), bf2f((unsigned short)u[j][5]),
                    bf2f((unsigned short)u[j][6]), bf2f((unsigned short)u[j][7])};
      l0 += vlo * w.x; h0 += vhi * w.x;
      l1 += vlo * w.y; h1 += vhi * w.y;
      l2 += vlo * w.z; h2 += vhi * w.z;
    }
  }
  if (e < end) {                           // tail chunk: clamped + weight-selected
    int2 se[8];
#pragma unroll
    for (int j = 0; j < 8; ++j) {
      int idx = e + j;
      se[j] = sorted_se[idx < end ? idx : end - 1];
    }
    bf16x8 u[8];
#pragma unroll
    for (int j = 0; j < 8; ++j)
      u[j] = *(const bf16x8*)(h_bf + (size_t)se[j].x * EMB + sub * 8);
#pragma unroll
    for (int j = 0; j < 8; ++j) {
      float4 w = (e + j < end) ? combo[se[j].y] : float4{0.f, 0.f, 0.f, 0.f};
      float4 vlo = {bf2f((unsigned short)u[j][0]), bf2f((unsigned short)u[j][1]),
                    bf2f((unsigned short)u[j][2]), bf2f((unsigned short)u[j][3])};
      float4 vhi = {bf2f((unsigned short)u[j][4]), bf2f((unsigned short)u[j][5]),
                    bf2f((unsigned short)u[j][6]), bf2f((unsigned short)u[j][7])};
      l0 += vlo * w.x; h0 += vhi * w.x;
      l1 += vlo * w.y; h1 += vhi * w.y;
      l2 += vlo * w.z; h2 += vhi * w.z;
    }
  }
  size_t base = (size_t)node * TDIM + sub * 8;
  *(bf16x8*)(t_bf + base)       = pack8(l0, h0);
  *(bf16x8*)(t_bf + base + 128) = pack8(l1, h1);
  *(bf16x8*)(t_bf + base + 256) = pack8(l2, h2);
}

// ---------------- MFMA GEMM: 64-row blocks (halved L2 weight re-fetch) ----------------
// Block 512 thr = 8 waves; 64 nodes/block; grid 782; LDS 50 KB -> 3 blocks/CU (24 waves).
// Wave wv owns cols wv*16..+15: 12 resident B-frags amortized over 4 row-tiles x 12
// MFMAs = 48 MFMAs (was 24). Per-layer L2 weight traffic 153 -> 77 MB.
// A-frag: A[m=lane&15][k=(lane>>4)*8+j]; B-frag: B[k][n=lane&15];
// C/D: col=lane&15, row=(lane>>4)*4+reg.
__global__ __launch_bounds__(512) void k_gemm(const unsigned short* __restrict__ t_bf,
                                              const unsigned short* __restrict__ wt,  // [128][384]
                                              const float* __restrict__ bl,  // [3][128]
                                              const unsigned short* __restrict__ h_in_bf,
                                              unsigned short* __restrict__ h_out_bf,
                                              int do_relu) {
  __shared__ unsigned short ts[GROWS * TS_LD];   // 50.2 KB
  const int nb = blockIdx.x * GROWS;
  for (int i = threadIdx.x; i < GROWS * 48; i += 512) {
    int r = i / 48, cc = i % 48;
    bf16x8 v = {};
    int row = nb + r;
    if (row < N_NODES) v = *(const bf16x8*)(t_bf + (size_t)row * TDIM + cc * 8);
    *(bf16x8*)(ts + r * TS_LD + cc * 8) = v;
  }
  __syncthreads();

  const int wv = threadIdx.x >> 6;
  const int lane = threadIdx.x & 63;
  const int m = lane & 15;
  const int kq = lane >> 4;
  const int c = wv * 16 + m;

  const unsigned short* pB = wt + (size_t)c * TDIM + kq * 8;
  bf16x8 B[12];
#pragma unroll
  for (int kc = 0; kc < 12; ++kc) B[kc] = *(const bf16x8*)(pB + kc * 32);

  const float bias = bl[c] + bl[128 + c] + bl[256 + c];

#pragma unroll
  for (int rt = 0; rt < 4; ++rt) {
    const unsigned short* pA = ts + (rt * 16 + m) * TS_LD + kq * 8;
    bf16x8 A[12];
#pragma unroll
    for (int kc = 0; kc < 12; ++kc) A[kc] = *(const bf16x8*)(pA + kc * 32);
    f32x4 acc = {0.f, 0.f, 0.f, 0.f};
#pragma unroll
    for (int kc = 0; kc < 12; ++kc) acc = MFMA_BF16(A[kc], B[kc], acc);
#pragma unroll
    for (int r = 0; r < 4; ++r) {
      int row = nb + rt * 16 + kq * 4 + r;
      if (row < N_NODES) {
        size_t idx = (size_t)row * EMB + c;
        float v = acc[r] + bias;
        if (do_relu) v = fmaxf(v, 0.f);
        float hn = bf2f(h_in_bf[idx]) + v;
        h_out_bf[idx] = f2bf(hn);
      }
    }
  }
}

// ---------------- fused mean-pool + head: block g reduces its contiguous node range ----------------
__global__ __launch_bounds__(128) void k_head(const unsigned short* __restrict__ h_bf,
                                              const int* __restrict__ gs,
                                              const float* __restrict__ fc1_w,
                                              const float* __restrict__ fc1_b,
                                              const float* __restrict__ fc2_w,
                                              const float* __restrict__ fc2_b,
                                              float* __restrict__ out) {
  __shared__ float hg[EMB];
  __shared__ float red[EMB];
  int g = blockIdx.x, e = threadIdx.x;
  int ns = gs[g], ne = gs[g + 1];
  float acc = 0.f;
  for (int n = ns; n < ne; ++n) acc += bf2f(h_bf[(size_t)n * EMB + e]);
  float cnt = fmaxf((float)(ne - ns), 1.f);
  hg[e] = acc / cnt;
  __syncthreads();
  float a2 = fc1_b[e];
  for (int j = 0; j < EMB; ++j) a2 += hg[j] * fc1_w[j * EMB + e];
  red[e] = a2 * fc2_w[e];
  __syncthreads();
  for (int s = 64; s > 0; s >>= 1) {
    if (e < s) red[e] += red[e + s];
    __syncthreads();
  }
  if (e == 0) out[g] = red[0] + fc2_b[0];
}

extern "C" void kernel_launch(void* const* d_in, const int* in_sizes, int n_in,
                              void* d_out, int out_size, void* d_ws, size_t ws_size,
                              hipStream_t stream) {
  const int*   x        = (const int*)d_in[0];
  const int*   ei       = (const int*)d_in[1];
  const int*   ea       = (const int*)d_in[2];
  const int*   batch    = (const int*)d_in[3];
  const float* atom_emb = (const float*)d_in[4];
  const float* bond_emb = (const float*)d_in[5];
  const float* W        = (const float*)d_in[6];
  const float* b        = (const float*)d_in[7];
  const float* fc1_w    = (const float*)d_in[8];
  const float* fc1_b    = (const float*)d_in[9];
  const float* fc2_w    = (const float*)d_in[10];
  const float* fc2_b    = (const float*)d_in[11];
  float* out = (float*)d_out;

  char* p = (char*)d_ws;
  auto alloc = [&](size_t bytes) { char* r = p; p += (bytes + 255) & ~(size_t)255; return r; };
  unsigned short* h0_bf      = (unsigned short*)alloc((size_t)HN * 2);
  unsigned short* h1_bf      = (unsigned short*)alloc((size_t)HN * 2);
  unsigned short* t_bf       = (unsigned short*)alloc((size_t)N_NODES * TDIM * 2);
  unsigned short* wt         = (unsigned short*)alloc((size_t)3 * 128 * TDIM * 2);
  int*            gs         = (int*)alloc((size_t)(N_GRAPHS + 1) * 4);
  int*            degP       = (int*)alloc((size_t)N_NODES * DEG_STRIDE * 4);  // 6.4 MB
  int*            rank       = (int*)alloc((size_t)N_EDGES * 4);
  int*            row_start  = (int*)alloc((size_t)(N_NODES + 1) * 4);
  int*            partials   = (int*)alloc(256 * 4);
  int2*           sorted_se  = (int2*)alloc((size_t)(N_EDGES + 8) * 8);

  hipMemsetAsync(degP, 0, (size_t)N_NODES * DEG_STRIDE * sizeof(int), stream);
  const int pre_blocks = PRE_ATOM_NB + PRE_HIST_NB + PRE_WCONV_NB + PRE_GB_NB;
  k_pre<<<pre_blocks, 384, 0, stream>>>(x, atom_emb, h0_bf, ei, degP, rank, W, wt, batch, gs);
  k_scan_a<<<SCAN_NB, 256, 0, stream>>>(degP, row_start, partials);
  k_scan_b<<<1, 256, 0, stream>>>(partials, row_start);
  k_scan_c<<<SCAN_NB, 256, 0, stream>>>(row_start, partials);
  k_scatter<<<(N_EDGES + 255) / 256, 256, 0, stream>>>(ei, ea, rank, row_start, sorted_se);

  unsigned short* hib = h0_bf;
  unsigned short* hob = h1_bf;
  const int gemm_blocks = (N_NODES + GROWS - 1) / GROWS;  // 782
  for (int layer = 0; layer < 3; ++layer) {
    k_agg<<<N_NODES / 16, 256, 0, stream>>>(sorted_se, row_start, bond_emb + layer * 72,
                                            hib, t_bf);
    k_gemm<<<gemm_blocks, 512, 0, stream>>>(
        t_bf, wt + (size_t)layer * 128 * TDIM, b + layer * 3 * EMB,
        hib, hob, layer < 2 ? 1 : 0);
    unsigned short* tb = hib; hib = hob; hob = tb;
  }
  // final h is in hib (h1_bf after 3 swaps)

  k_head<<<N_GRAPHS, 128, 0, stream>>>(hib, gs, fc1_w, fc1_b, fc2_w, fc2_b, out);
}